// Round 9
// baseline (136.318 us; speedup 1.0000x reference)
//
#include <hip/hip_runtime.h>
#include <math.h>

// Problem constants: bs=64, n=16384, dx=128, dy=256
#define BS     64
#define NN     16384
#define DX     128
#define DY     256
#define ZDIM   (4 * DX)          // 512
#define NCHUNK 8
#define ROWS_PER_CHUNK (NN / NCHUNK)   // 2048

typedef float floatx4 __attribute__((ext_vector_type(4)));

// ---------------------------------------------------------------------------
// Single fused kernel. Grid (BS, NCHUNK) = 512 blocks = 2 blocks/CU (8
// waves/CU — R8 proved this occupancy streams at full rate).
// Phase 1: R8's proven streaming loop: thread t owns column quad q=t&31;
//   row-group rg=t>>5 walks a contiguous 256-row span at 512B stride with
//   NT float4 loads (R3vR5: NT = +16%). LDS-reduce -> partials ws[b][c][*].
// Gate: thread0 release-fence + atomicAdd(&cnt[b],1). (ticket&7)==7 selects
//   EXACTLY ONE block per batch per launch regardless of cnt's initial value
//   (any 8 consecutive integers contain exactly one = 7 mod 8) -> stateless,
//   poison-proof, no memset.
// Phase 2 (one block per batch): acquire-fence, reduce 8 chunk partials in
//   FIXED order (deterministic), build z, out = z@W^T + bias. Overlaps other
//   batches' streaming; no tail kernel, no launch gap.
// NOTE: __launch_bounds__(256) ONLY — R6 proved (256,8)'s 64-VGPR cap spills
//   the hot loop (111 -> 214 us). At 2 blocks/CU VGPR cannot limit occupancy.
// ---------------------------------------------------------------------------
__global__ __launch_bounds__(256) void stats_fused(
    const float* __restrict__ X, const float* __restrict__ W,
    const float* __restrict__ bias, float* ws, unsigned* cnt, float* out) {
    const int b = blockIdx.x;
    const int c = blockIdx.y;
    const int t = threadIdx.x;
    const int q = t & 31;    // column quad (cols 4q..4q+3)
    const int rg = t >> 5;   // row group 0..7 -> rows [rg*256, rg*256+256)

    const floatx4* __restrict__ Xt = (const floatx4*)(
        X + (size_t)b * NN * DX + (size_t)c * ROWS_PER_CHUNK * DX) +
        (size_t)rg * 256 * 32 + q;

    float s0 = 0.f, s1 = 0.f, s2 = 0.f, s3 = 0.f;       // sum
    float p0 = 0.f, p1 = 0.f, p2 = 0.f, p3 = 0.f;       // sum of squares
    float mn0 = INFINITY, mn1 = INFINITY, mn2 = INFINITY, mn3 = INFINITY;
    float mx0 = -INFINITY, mx1 = -INFINITY, mx2 = -INFINITY, mx3 = -INFINITY;

    #pragma unroll 8
    for (int s = 0; s < 256; ++s) {
        floatx4 v = __builtin_nontemporal_load(Xt + (size_t)s * 32);
        s0 += v.x; p0 += v.x * v.x; mn0 = fminf(mn0, v.x); mx0 = fmaxf(mx0, v.x);
        s1 += v.y; p1 += v.y * v.y; mn1 = fminf(mn1, v.y); mx1 = fmaxf(mx1, v.y);
        s2 += v.z; p2 += v.z * v.z; mn2 = fminf(mn2, v.z); mx2 = fmaxf(mx2, v.z);
        s3 += v.w; p3 += v.w * v.w; mn3 = fminf(mn3, v.w); mx3 = fmaxf(mx3, v.w);
    }

    // LDS: [group][quad][16: sum0..3, sumsq0..3, min0..3, max0..3] (16 KB)
    __shared__ float lds[8][32][16];
    __shared__ unsigned last_flag;
    float* L = lds[rg][q];
    L[0] = s0;  L[1] = s1;  L[2] = s2;  L[3] = s3;
    L[4] = p0;  L[5] = p1;  L[6] = p2;  L[7] = p3;
    L[8] = mn0; L[9] = mn1; L[10] = mn2; L[11] = mn3;
    L[12] = mx0; L[13] = mx1; L[14] = mx2; L[15] = mx3;
    __syncthreads();

    // Reduce across the 8 row-groups; write partials ws[b][c][comp][d].
    for (int v = t; v < 512; v += 256) {
        const int comp = v >> 7;       // 0..3
        const int d = v & 127;
        const int qq = d >> 2;
        const int idx = comp * 4 + (d & 3);
        float r = lds[0][qq][idx];
        #pragma unroll
        for (int k = 1; k < 8; ++k) {
            const float x = lds[k][qq][idx];
            if (comp < 2)       r += x;
            else if (comp == 2) r = fminf(r, x);
            else                r = fmaxf(r, x);
        }
        ws[(((size_t)b * NCHUNK + c) * 4 + comp) * DX + d] = r;
    }
    __syncthreads();   // all partial stores issued block-wide

    // ---- gate: exactly one block per batch proceeds ----
    if (t == 0) {
        __threadfence();   // release: partials visible device-wide
        const unsigned ticket = atomicAdd(&cnt[b], 1u);
        last_flag = ((ticket & 7u) == 7u) ? 1u : 0u;
    }
    __syncthreads();
    if (!last_flag) return;
    __threadfence();       // acquire: don't read stale partials

    // ---- phase 2: fixed-order reduce of 8 chunk partials ----
    float* red = &lds[0][0][0];   // 512 floats (reuse LDS)
    float* z   = red + 512;       // 512 floats

    for (int v = t; v < 512; v += 256) {
        const int comp = v >> 7;
        const int d = v & 127;
        const float* p = ws + (((size_t)b * NCHUNK) * 4 + comp) * DX + d;
        float r = p[0];
        #pragma unroll
        for (int cc = 1; cc < NCHUNK; ++cc) {
            const float x = p[(size_t)cc * 512];
            if (comp < 2)       r += x;
            else if (comp == 2) r = fminf(r, x);
            else                r = fmaxf(r, x);
        }
        red[v] = r;
    }
    __syncthreads();

    if (t < DX) {
        const float s  = red[t];
        const float ss = red[DX + t];
        const float mean = s / (float)NN;
        const float var  = (ss - s * s / (float)NN) / (float)(NN - 1);
        z[t]            = mean;                    // mean
        z[DX + t]       = red[2 * DX + t];         // min
        z[2 * DX + t]   = red[3 * DX + t];         // max
        z[3 * DX + t]   = sqrtf(fmaxf(var, 0.f));  // std (ddof=1)
    }
    __syncthreads();

    // out[b][o] = bias[o] + dot(z, W[o][:])
    const int o = t;  // 256 outputs, 256 threads
    const float4* __restrict__ Wr = (const float4*)(W + (size_t)o * ZDIM);
    const float4* zz = (const float4*)z;
    float acc = bias[o];
    #pragma unroll 8
    for (int k = 0; k < ZDIM / 4; ++k) {
        const float4 w4 = Wr[k];
        const float4 zv = zz[k];
        acc += w4.x * zv.x + w4.y * zv.y + w4.z * zv.z + w4.w * zv.w;
    }
    out[(size_t)b * DY + o] = acc;
}

extern "C" void kernel_launch(void* const* d_in, const int* in_sizes, int n_in,
                              void* d_out, int out_size, void* d_ws, size_t ws_size,
                              hipStream_t stream) {
    const float* X    = (const float*)d_in[0];   // [64, 16384, 128] fp32
    const float* W    = (const float*)d_in[1];   // [256, 512] fp32
    const float* bias = (const float*)d_in[2];   // [256] fp32
    float* out        = (float*)d_out;           // [64, 256] fp32
    float* ws         = (float*)d_ws;            // partials: 1 MiB
    unsigned* cnt     = (unsigned*)((char*)d_ws + (1u << 20));  // 64 u32

    dim3 grid(BS, NCHUNK);
    stats_fused<<<grid, 256, 0, stream>>>(X, W, bias, ws, cnt, out);
}